// Round 9
// baseline (675.235 us; speedup 1.0000x reference)
//
#include <hip/hip_runtime.h>

#define SEQn 33
#define Fn   20480
#define Hn   900
#define Bn   2
#define WVn  100
#define OBJn 35
#define RELn 82
#define G4n  3600
#define Mn   66
#define NBLK 225

// ---- K1 MFMA geometry (round-7, proven)
#define KS1  16
#define KSL1 (Fn/KS1)      // 1280
#define RB1  15
#define RPB1 240
#define NC1  (KSL1/32)     // 40
#define WSTR 40

typedef __attribute__((ext_vector_type(8))) short bf16x8;
typedef __attribute__((ext_vector_type(4))) float f32x4;

__device__ __forceinline__ float sigf(float v){ return 1.f/(1.f+expf(-v)); }
__device__ __forceinline__ float dot4(float4 a, float4 b){ return a.x*b.x+a.y*b.y+a.z*b.z+a.w*b.w; }
__device__ __forceinline__ float wred(float v){
  #pragma unroll
  for (int d = 32; d >= 1; d >>= 1) v += __shfl_xor(v, d, 64);
  return v;
}
__device__ __forceinline__ float gload(const float* p){
  return __hip_atomic_load((const float*)p, __ATOMIC_RELAXED, __HIP_MEMORY_SCOPE_AGENT);
}
__device__ __forceinline__ void gstore(float* p, float v){
  __hip_atomic_store(p, v, __ATOMIC_RELAXED, __HIP_MEMORY_SCOPE_AGENT);
}
__device__ __forceinline__ unsigned short f2bf(float f){
  unsigned u = __float_as_uint(f);
  unsigned r = u + 0x7FFFu + ((u >> 16) & 1u);
  return (unsigned short)(r >> 16);
}
__device__ __forceinline__ float bf2f(unsigned short h){
  return __uint_as_float(((unsigned)h) << 16);
}

// lightweight grid barrier: relaxed agent atomics only (proven rounds 5-7)
__device__ __forceinline__ void gbar(unsigned* bar){
  __syncthreads();
  if (threadIdx.x == 0) {
    unsigned g = __hip_atomic_load(&bar[0], __ATOMIC_RELAXED, __HIP_MEMORY_SCOPE_AGENT);
    unsigned cnt = __hip_atomic_fetch_add(&bar[32], 1u, __ATOMIC_RELAXED, __HIP_MEMORY_SCOPE_AGENT);
    if (cnt == (unsigned)(NBLK-1)) {
      __hip_atomic_store(&bar[32], 0u, __ATOMIC_RELAXED, __HIP_MEMORY_SCOPE_AGENT);
      asm volatile("s_waitcnt vmcnt(0)" ::: "memory");
      __hip_atomic_store(&bar[0], g+1u, __ATOMIC_RELAXED, __HIP_MEMORY_SCOPE_AGENT);
    } else {
      unsigned cur;
      do { __builtin_amdgcn_s_sleep(8);
           cur = __hip_atomic_load(&bar[0], __ATOMIC_RELAXED, __HIP_MEMORY_SCOPE_AGENT);
      } while (cur == g);
    }
  }
  __syncthreads();
}

// ---------------- K1 (round-7 verbatim, proven)
__global__ __launch_bounds__(320) void k1_mfma(
    const float* __restrict__ x, const float* __restrict__ w1,
    float* __restrict__ G1, unsigned* __restrict__ bar)
{
  const int tid = threadIdx.x;
  if (blockIdx.x == 0 && tid == 0) {
    __hip_atomic_store(&bar[0], 0u, __ATOMIC_RELAXED, __HIP_MEMORY_SCOPE_AGENT);
    __hip_atomic_store(&bar[32], 0u, __ATOMIC_RELAXED, __HIP_MEMORY_SCOPE_AGENT);
  }
  __shared__ unsigned short WhL[2][RPB1*WSTR], WlL[2][RPB1*WSTR];
  __shared__ unsigned short XhL[2][80*WSTR],  XlL[2][80*WSTR];

  const int rb = blockIdx.x % RB1;
  const int ks = blockIdx.x / RB1;
  const int r0 = rb * RPB1;
  const int kofs = ks * KSL1;
  const int wv_ = tid >> 6;
  const int lane = tid & 63;
  const int p = lane & 15;
  const int q = lane >> 4;

  f32x4 acc[3][5];
  #pragma unroll
  for (int rt = 0; rt < 3; ++rt)
    #pragma unroll
    for (int mt = 0; mt < 5; ++mt) acc[rt][mt] = (f32x4){0.f,0.f,0.f,0.f};

  float4 wr[6], xrg[2];

  #define ISSUE_STAGE(cc)                                                      \
    { const int kbase = kofs + (cc)*32;                                        \
      _Pragma("unroll")                                                        \
      for (int u = 0; u < 6; ++u) {                                            \
        const int idx = tid + u*320;                                           \
        const int row = idx >> 3, k4 = idx & 7;                                \
        wr[u] = *(const float4*)(w1 + (size_t)(r0+row)*Fn + kbase + k4*4);     \
      }                                                                        \
      _Pragma("unroll")                                                        \
      for (int u = 0; u < 2; ++u) {                                            \
        const int idx = tid + u*320;                                           \
        const int mrow = idx >> 3, k4 = idx & 7;                               \
        xrg[u] = (mrow < Mn)                                                   \
          ? *(const float4*)(x + (size_t)mrow*Fn + kbase + k4*4)               \
          : make_float4(0.f,0.f,0.f,0.f);                                      \
      }                                                                        \
    }

  #define CVTW(dsth, dstl, off, v)                                             \
    { const unsigned short h0=f2bf(v.x), h1=f2bf(v.y), h2=f2bf(v.z), h3=f2bf(v.w); \
      const unsigned short l0=f2bf(v.x-bf2f(h0)), l1=f2bf(v.y-bf2f(h1));       \
      const unsigned short l2=f2bf(v.z-bf2f(h2)), l3=f2bf(v.w-bf2f(h3));       \
      *(uint2*)&dsth[off] = make_uint2((unsigned)h0|((unsigned)h1<<16),        \
                                       (unsigned)h2|((unsigned)h3<<16));       \
      *(uint2*)&dstl[off] = make_uint2((unsigned)l0|((unsigned)l1<<16),        \
                                       (unsigned)l2|((unsigned)l3<<16));       \
    }

  #define WRITE_STAGE(bb)                                                     \
    { _Pragma("unroll")                                                       \
      for (int u = 0; u < 6; ++u) {                                           \
        const int idx = tid + u*320;                                          \
        const int row = idx >> 3, k4 = idx & 7;                               \
        CVTW(WhL[bb], WlL[bb], row*WSTR + k4*4, wr[u]);                       \
      }                                                                       \
      _Pragma("unroll")                                                       \
      for (int u = 0; u < 2; ++u) {                                           \
        const int idx = tid + u*320;                                          \
        const int mrow = idx >> 3, k4 = idx & 7;                              \
        CVTW(XhL[bb], XlL[bb], mrow*WSTR + k4*4, xrg[u]);                     \
      }                                                                       \
    }

  ISSUE_STAGE(0);
  WRITE_STAGE(0);
  __syncthreads();

  for (int c = 0; c < NC1; ++c) {
    const int buf = c & 1;
    if (c+1 < NC1) ISSUE_STAGE(c+1);

    bf16x8 Bh[5], Bl[5];
    #pragma unroll
    for (int mt = 0; mt < 5; ++mt) {
      const int moff = (mt*16 + p)*WSTR + q*8;
      Bh[mt] = *(const bf16x8*)&XhL[buf][moff];
      Bl[mt] = *(const bf16x8*)&XlL[buf][moff];
    }
    #pragma unroll
    for (int rt = 0; rt < 3; ++rt) {
      const int roff = ((wv_ + 5*rt)*16 + p)*WSTR + q*8;
      const bf16x8 Ah = *(const bf16x8*)&WhL[buf][roff];
      const bf16x8 Al = *(const bf16x8*)&WlL[buf][roff];
      #pragma unroll
      for (int mt = 0; mt < 5; ++mt) {
        acc[rt][mt] = __builtin_amdgcn_mfma_f32_16x16x32_bf16(Ah, Bh[mt], acc[rt][mt], 0, 0, 0);
        acc[rt][mt] = __builtin_amdgcn_mfma_f32_16x16x32_bf16(Ah, Bl[mt], acc[rt][mt], 0, 0, 0);
        acc[rt][mt] = __builtin_amdgcn_mfma_f32_16x16x32_bf16(Al, Bh[mt], acc[rt][mt], 0, 0, 0);
      }
    }

    if (c+1 < NC1) WRITE_STAGE(buf^1);
    __syncthreads();
  }

  #pragma unroll
  for (int rt = 0; rt < 3; ++rt)
    #pragma unroll
    for (int mt = 0; mt < 5; ++mt) {
      const int m = mt*16 + p;
      if (m < Mn) {
        #pragma unroll
        for (int r4 = 0; r4 < 4; ++r4) {
          const int grow = r0 + (wv_ + 5*rt)*16 + q*4 + r4;
          atomicAdd(&G1[(size_t)grow*Mn + m], acc[rt][mt][r4]);
        }
      }
    }
  #undef ISSUE_STAGE
  #undef WRITE_STAGE
  #undef CVTW
}

// ---------------- K2 (cooperative, 225 x 512): L1 step i ∥ L2 step i-1.
// Double-buffered weight registers; issue placed after the post-staging barrier
// so the transfer flies under A-dots + B-dots (compiler drains at next barrier).
__global__ __launch_bounds__(512) void k_rec(
    const float* __restrict__ G1, float* __restrict__ out1, float* __restrict__ h2buf,
    const float* __restrict__ whh1,
    const float* __restrict__ wih2, const float* __restrict__ whh2,
    const float* __restrict__ bih2, const float* __restrict__ bhh2,
    const float* __restrict__ bih1, const float* __restrict__ bhh1,
    const float* __restrict__ wobj1, const float* __restrict__ bobj1,
    const float* __restrict__ wrel,  const float* __restrict__ brel,
    const float* __restrict__ wobj2, const float* __restrict__ bobj2,
    const float* __restrict__ embed, float* __restrict__ dout,
    unsigned* __restrict__ bar)
{
  __shared__ float hls[Bn][904];
  __shared__ float h2l[Bn][904];
  __shared__ float wvls[Bn][104];
  __shared__ float gls[16][68];
  __shared__ float bls[SEQn][16];
  __shared__ float gexA[16][Bn], gexB[16][Bn];
  __shared__ float cA[4][Bn], cB[4][Bn];
  __shared__ float red[4];
  __shared__ int idxls[Bn];

  const int tid = threadIdx.x;
  const int blk = blockIdx.x;
  const int j0 = blk * 4;
  const int wv_ = tid >> 6;
  const int lane = tid & 63;

  if (tid < 8) {
    const int jj = tid >> 1, m = tid & 1;
    cA[jj][m] = 0.f; cB[jj][m] = 0.f;
    gstore(h2buf + (size_t)m*Hn + j0 + jj, 0.f);
  }

  for (int qq = tid; qq < 16*Mn; qq += 512) {
    const int rho = qq / Mn, t = qq % Mn;
    const int gate = rho >> 2, jj = rho & 3;
    const size_t rA = (size_t)gate*Hn + j0 + jj;
    gls[rho][t] = G1[rA*Mn + t] + bih1[rA] + bhh1[rA];
  }
  for (int qq = tid; qq < SEQn*16; qq += 512) {
    const int s = qq / 16, rho = qq % 16;
    const int gate = rho >> 2, jj = rho & 3;
    const size_t ro = (size_t)s*G4n + (size_t)gate*Hn + j0 + jj;
    bls[s][rho] = bih2[ro] + bhh2[ro];
  }

  float4 wAreg[2][4];
  #pragma unroll
  for (int ri = 0; ri < 2; ++ri) {
    const int rho = wv_*2 + ri;
    const int gate = rho >> 2, jj = rho & 3;
    const size_t row = (size_t)gate*Hn + j0 + jj;
    #pragma unroll
    for (int e = 0; e < 4; ++e) {
      const int k = lane*4 + e*256;
      wAreg[ri][e] = (k <= Hn-4) ? *(const float4*)(whh1 + row*Hn + k)
                                 : make_float4(0.f,0.f,0.f,0.f);
    }
  }

  // double-buffered L2 weight prefetch registers (statically indexed)
  float4 wiR0[2][4], whR0[2][4], wiR1[2][4], whR1[2][4];
  #define ISSUE_W(sp, WI, WH)                                                \
    { _Pragma("unroll")                                                      \
      for (int ri = 0; ri < 2; ++ri) {                                       \
        const int rho = wv_*2 + ri;                                          \
        const int gate = rho >> 2, jj = rho & 3;                             \
        const size_t ro = (size_t)(sp)*G4n + (size_t)gate*Hn + j0 + jj;      \
        const float* wI = wih2 + ro*1000;                                    \
        const float* wH = whh2 + ro*Hn;                                      \
        _Pragma("unroll")                                                    \
        for (int e = 0; e < 4; ++e) {                                        \
          const int k = lane*4 + e*256;                                      \
          if (k <= 996) WI[ri][e] = *(const float4*)(wI + k);                \
          if (k <= 896) WH[ri][e] = *(const float4*)(wH + k);                \
        }                                                                    \
      }                                                                      \
    }

  #define ADOTS(ivar)                                                        \
    { _Pragma("unroll")                                                      \
      for (int ri = 0; ri < 2; ++ri) {                                       \
        const int rho = wv_*2 + ri;                                          \
        float a0 = 0.f, a1 = 0.f;                                            \
        _Pragma("unroll")                                                    \
        for (int e = 0; e < 4; ++e) {                                        \
          const int k = lane*4 + e*256;                                      \
          if (k <= Hn-4) {                                                   \
            a0 += dot4(wAreg[ri][e], *(const float4*)&hls[0][k]);            \
            a1 += dot4(wAreg[ri][e], *(const float4*)&hls[1][k]);            \
          }                                                                  \
        }                                                                    \
        a0 = wred(a0); a1 = wred(a1);                                        \
        if (lane == 0) {                                                     \
          gexA[rho][0] = a0 + gls[rho][(ivar)*Bn + 0];                       \
          gexA[rho][1] = a1 + gls[rho][(ivar)*Bn + 1];                       \
        }                                                                    \
      }                                                                      \
    }

  #define BDOTS(svar, WI, WH, USEWV)                                         \
    { _Pragma("unroll")                                                      \
      for (int ri = 0; ri < 2; ++ri) {                                       \
        const int rho = wv_*2 + ri;                                          \
        float b0 = 0.f, b1 = 0.f;                                            \
        _Pragma("unroll")                                                    \
        for (int e = 0; e < 4; ++e) {                                        \
          const int k = lane*4 + e*256;                                      \
          if (k <= 896) {                                                    \
            b0 += dot4(WI[ri][e], *(const float4*)&hls[0][k]);               \
            b1 += dot4(WI[ri][e], *(const float4*)&hls[1][k]);               \
            b0 += dot4(WH[ri][e], *(const float4*)&h2l[0][k]);               \
            b1 += dot4(WH[ri][e], *(const float4*)&h2l[1][k]);               \
          } else if ((USEWV) && k >= 900 && k <= 996) {                      \
            b0 += dot4(WI[ri][e], *(const float4*)&wvls[0][k-900]);          \
            b1 += dot4(WI[ri][e], *(const float4*)&wvls[1][k-900]);          \
          }                                                                  \
        }                                                                    \
        b0 = wred(b0); b1 = wred(b1);                                        \
        if (lane == 0) {                                                     \
          const float bb = bls[svar][rho];                                   \
          gexB[rho][0] = b0 + bb;                                            \
          gexB[rho][1] = b1 + bb;                                            \
        }                                                                    \
      }                                                                      \
    }

  #define UPD_A(ivar)                                                        \
    { const float cc = sigf(gexA[4+jj][m])*cA[jj][m]                         \
                     + sigf(gexA[jj][m])*tanhf(gexA[8+jj][m]);               \
      cA[jj][m] = cc;                                                        \
      gstore(out1 + ((size_t)(ivar)*Bn + m)*Hn + j0 + jj,                    \
             sigf(gexA[12+jj][m])*tanhf(cc)); }

  #define UPD_B(svar)                                                        \
    { const float cc = sigf(gexB[4+jj][m])*cB[jj][m]                         \
                     + sigf(gexB[jj][m])*tanhf(gexB[8+jj][m]);               \
      cB[jj][m] = cc;                                                        \
      gstore(h2buf + ((size_t)(((svar)+1)&1)*Bn + m)*Hn + j0 + jj,           \
             sigf(gexB[12+jj][m])*tanhf(cc)); }

  #define STAGE_STEADY(ivar)                                                 \
    { for (int qq = tid; qq < 1808; qq += 512) {                             \
        const int m = qq / 904, kk = qq % 904;                               \
        hls[m][kk] = (kk < 900)                                              \
          ? gload(out1 + ((size_t)((ivar)-1)*Bn + m)*Hn + kk) : 0.f;         \
      }                                                                      \
      for (int qq = tid; qq < 1808; qq += 512) {                             \
        const int m = qq / 904, kk = qq % 904;                               \
        h2l[m][kk] = (kk < 900)                                              \
          ? gload(h2buf + ((size_t)(((ivar)-1)&1)*Bn + m)*Hn + kk) : 0.f;    \
      } }

  // steady interval: stage -> sync -> issue W(i) into ALT -> dots -> sync -> update -> gbar
  #define STEADY(ivar, WIu, WHu, WIa, WHa)                                   \
    { STAGE_STEADY(ivar);                                                    \
      __syncthreads();                                                       \
      ISSUE_W((ivar), WIa, WHa);                                             \
      ADOTS(ivar);                                                           \
      BDOTS((ivar)-1, WIu, WHu, 0);                                          \
      __syncthreads();                                                       \
      if (tid < 8) {                                                         \
        const int jj = tid >> 1, m = tid & 1;                                \
        UPD_A(ivar);                                                         \
        UPD_B((ivar)-1);                                                     \
      }                                                                      \
      gbar(bar); }

  ISSUE_W(0, wiR0, whR0);     // step-0 weights into buf0 (drained once, prologue)
  __syncthreads();            // gls/bls ready

  // ---- interval 0: A step 0 only (h_prev = 0 -> A-dot contribution = 0)
  if (lane == 0) {
    #pragma unroll
    for (int ri = 0; ri < 2; ++ri) {
      const int rho = wv_*2 + ri;
      gexA[rho][0] = gls[rho][0];
      gexA[rho][1] = gls[rho][1];
    }
  }
  __syncthreads();
  if (tid < 8) { const int jj = tid >> 1, m = tid & 1; UPD_A(0); }
  gbar(bar);

  // ---- steady intervals 1..31 (15 pairs + 1), static buffer alternation
  for (int ib = 1; ib <= 29; ib += 2) {
    STEADY(ib,   wiR0, whR0, wiR1, whR1);
    STEADY(ib+1, wiR1, whR1, wiR0, whR0);
  }
  STEADY(31, wiR0, whR0, wiR1, whR1);   // consumes W(30), issues W(31) -> buf1

  // ---- tail: i = 32..36 (heads, argmax feedback, last two L2 steps)
  for (int i = 32; i < 37; ++i) {
    if (i == 33 || i == 35) {        // argmax + word vector
      if (wv_ < 2) {
        const int m = wv_;
        const int nout = (i == 33) ? OBJn : RELn;
        const int off = (i == 33) ? 0 : Bn*OBJn;
        float v = -1e30f; int idx = 0;
        for (int o = lane; o < nout; o += 64) {
          float t = gload(dout + off + m*nout + o);
          if (t > v) { v = t; idx = o; }
        }
        #pragma unroll
        for (int d = 32; d >= 1; d >>= 1) {
          float ov = __shfl_xor(v, d, 64);
          int   oi = __shfl_xor(idx, d, 64);
          if (ov > v || (ov == v && oi < idx)) { v = ov; idx = oi; }
        }
        if (lane == 0) idxls[m] = idx + ((i == 35) ? OBJn : 0);
      }
      __syncthreads();
      for (int qq = tid; qq < Bn*104; qq += 512) {
        const int m = qq / 104, v4 = qq % 104;
        wvls[m][v4] = (v4 < WVn) ? embed[(size_t)idxls[m]*WVn + v4] : 0.f;
      }
      __syncthreads();
    }

    const bool hasA = (i == 32);
    const int  s = (i == 33) ? 31 : (i == 35) ? 32 : -1;
    const bool hasB = (s >= 0);
    const int  srcA = (i == 35) ? 32 : i-1;

    if (hasA || i == 35) {
      for (int qq = tid; qq < 1808; qq += 512) {
        const int m = qq / 904, kk = qq % 904;
        hls[m][kk] = (kk < 900)
          ? gload(out1 + ((size_t)srcA*Bn + m)*Hn + kk) : 0.f;
      }
    }
    if (hasB) {
      for (int qq = tid; qq < 1808; qq += 512) {
        const int m = qq / 904, kk = qq % 904;
        h2l[m][kk] = (kk < 900)
          ? gload(h2buf + ((size_t)(s&1)*Bn + m)*Hn + kk) : 0.f;
      }
    }
    __syncthreads();

    if (hasA) ADOTS(32);
    if (i == 33) { BDOTS(31, wiR1, whR1, 1); ISSUE_W(32, wiR0, whR0); }
    if (i == 35) { BDOTS(32, wiR0, whR0, 1); }

    if (i == 32 || i == 34 || i == 36) {   // heads: obj1 / rel / obj2
      const int nout = (i == 34) ? RELn : OBJn;
      const float* wh  = (i == 32) ? wobj1 : (i == 34) ? wrel : wobj2;
      const float* bh_ = (i == 32) ? bobj1 : (i == 34) ? brel : bobj2;
      const int off = (i == 32) ? 0 : (i == 34) ? (Bn*OBJn) : (Bn*OBJn + Bn*RELn);
      const int hb = (i == 34) ? 0 : 1;
      if (blk < nout*Bn) {
        const int o = blk >> 1, m = blk & 1;
        float p = 0.f;
        if (tid < 225) {
          const float4 wv4 = *(const float4*)(wh + (size_t)o*Hn + tid*4);
          float* hp = h2buf + ((size_t)hb*Bn + m)*Hn + tid*4;
          p = wv4.x*gload(hp+0) + wv4.y*gload(hp+1)
            + wv4.z*gload(hp+2) + wv4.w*gload(hp+3);
        }
        if (wv_ < 4) {
          const float pr = wred(p);
          if (lane == 0) red[wv_] = pr;
        }
        __syncthreads();
        if (tid == 0)
          gstore(&dout[off + m*nout + o], red[0]+red[1]+red[2]+red[3] + bh_[o]);
      }
    }

    __syncthreads();
    if (tid < 8) {
      const int jj = tid >> 1, m = tid & 1;
      if (hasA) UPD_A(32);
      if (i == 33) UPD_B(31);
      if (i == 35) UPD_B(32);
    }

    if (i < 36) gbar(bar);
  }
  #undef ISSUE_W
  #undef ADOTS
  #undef BDOTS
  #undef UPD_A
  #undef UPD_B
  #undef STAGE_STEADY
  #undef STEADY
}

extern "C" void kernel_launch(void* const* d_in, const int* in_sizes, int n_in,
                              void* d_out, int out_size, void* d_ws, size_t ws_size,
                              hipStream_t stream)
{
  (void)in_sizes; (void)n_in; (void)out_size; (void)ws_size;
  const float* x     = (const float*)d_in[0];
  const float* wih1  = (const float*)d_in[1];
  const float* whh1  = (const float*)d_in[2];
  const float* bih1  = (const float*)d_in[3];
  const float* bhh1  = (const float*)d_in[4];
  const float* wih2  = (const float*)d_in[5];
  const float* whh2  = (const float*)d_in[6];
  const float* bih2  = (const float*)d_in[7];
  const float* bhh2  = (const float*)d_in[8];
  const float* wobj1 = (const float*)d_in[9];
  const float* bobj1 = (const float*)d_in[10];
  const float* wrel  = (const float*)d_in[11];
  const float* brel  = (const float*)d_in[12];
  const float* wobj2 = (const float*)d_in[13];
  const float* bobj2 = (const float*)d_in[14];
  const float* embed = (const float*)d_in[15];
  float* dout = (float*)d_out;

  float* ws = (float*)d_ws;
  float* G1    = ws;
  float* out1  = G1 + (size_t)G4n*Mn;
  float* h2buf = out1 + (size_t)SEQn*Bn*Hn;
  unsigned* bar = (unsigned*)(h2buf + (size_t)2*Bn*Hn);

  hipMemsetAsync(G1, 0, (size_t)G4n*Mn*sizeof(float), stream);
  hipLaunchKernelGGL(k1_mfma, dim3(RB1*KS1), dim3(320), 0, stream, x, wih1, G1, bar);

  void* args[19];
  args[0]  = (void*)&G1;    args[1]  = (void*)&out1;  args[2]  = (void*)&h2buf;
  args[3]  = (void*)&whh1;  args[4]  = (void*)&wih2;  args[5]  = (void*)&whh2;
  args[6]  = (void*)&bih2;  args[7]  = (void*)&bhh2;  args[8]  = (void*)&bih1;
  args[9]  = (void*)&bhh1;  args[10] = (void*)&wobj1; args[11] = (void*)&bobj1;
  args[12] = (void*)&wrel;  args[13] = (void*)&brel;  args[14] = (void*)&wobj2;
  args[15] = (void*)&bobj2; args[16] = (void*)&embed; args[17] = (void*)&dout;
  args[18] = (void*)&bar;
  hipLaunchCooperativeKernel((void*)k_rec, dim3(NBLK), dim3(512), args, 0, stream);
}

// Round 10
// 500.186 us; speedup vs baseline: 1.3500x; 1.3500x over previous
//
#include <hip/hip_runtime.h>

#define SEQn 33
#define Fn   20480
#define Hn   900
#define Bn   2
#define WVn  100
#define OBJn 35
#define RELn 82
#define G4n  3600
#define Mn   66
#define NBLK 225

// ---- K1 MFMA geometry (round-7, proven)
#define KS1  16
#define KSL1 (Fn/KS1)      // 1280
#define RB1  15
#define RPB1 240
#define NC1  (KSL1/32)     // 40
#define WSTR 40

typedef __attribute__((ext_vector_type(8))) short bf16x8;
typedef __attribute__((ext_vector_type(4))) float f32x4;

__device__ __forceinline__ float sigf(float v){ return 1.f/(1.f+expf(-v)); }
__device__ __forceinline__ float dot4(float4 a, float4 b){ return a.x*b.x+a.y*b.y+a.z*b.z+a.w*b.w; }
__device__ __forceinline__ float wred(float v){
  #pragma unroll
  for (int d = 32; d >= 1; d >>= 1) v += __shfl_xor(v, d, 64);
  return v;
}
__device__ __forceinline__ float gload(const float* p){
  return __hip_atomic_load((const float*)p, __ATOMIC_RELAXED, __HIP_MEMORY_SCOPE_AGENT);
}
__device__ __forceinline__ void gstore(float* p, float v){
  __hip_atomic_store(p, v, __ATOMIC_RELAXED, __HIP_MEMORY_SCOPE_AGENT);
}
__device__ __forceinline__ unsigned short f2bf(float f){
  unsigned u = __float_as_uint(f);
  unsigned r = u + 0x7FFFu + ((u >> 16) & 1u);
  return (unsigned short)(r >> 16);
}
__device__ __forceinline__ float bf2f(unsigned short h){
  return __uint_as_float(((unsigned)h) << 16);
}

// full-drain grid barrier (proven rounds 5-9) — used at i=0 and tail
__device__ __forceinline__ void gbar(unsigned* bar){
  __syncthreads();
  if (threadIdx.x == 0) {
    unsigned g = __hip_atomic_load(&bar[0], __ATOMIC_RELAXED, __HIP_MEMORY_SCOPE_AGENT);
    unsigned cnt = __hip_atomic_fetch_add(&bar[32], 1u, __ATOMIC_RELAXED, __HIP_MEMORY_SCOPE_AGENT);
    if (cnt == (unsigned)(NBLK-1)) {
      __hip_atomic_store(&bar[32], 0u, __ATOMIC_RELAXED, __HIP_MEMORY_SCOPE_AGENT);
      asm volatile("s_waitcnt vmcnt(0)" ::: "memory");
      __hip_atomic_store(&bar[0], g+1u, __ATOMIC_RELAXED, __HIP_MEMORY_SCOPE_AGENT);
    } else {
      unsigned cur;
      do { __builtin_amdgcn_s_sleep(1);
           cur = __hip_atomic_load(&bar[0], __ATOMIC_RELAXED, __HIP_MEMORY_SCOPE_AGENT);
      } while (cur == g);
    }
  }
  __syncthreads();
}

// partial-drain grid barrier: only wave 0 (sole global-storing wave) drains vmcnt,
// so other waves' in-flight weight prefetch loads survive the barrier.
__device__ __forceinline__ void gbar_lite(unsigned* bar, int wv){
  asm volatile("" ::: "memory");
  if (wv == 0) asm volatile("s_waitcnt vmcnt(0)" ::: "memory");
  __builtin_amdgcn_sched_barrier(0);
  __builtin_amdgcn_s_barrier();
  __builtin_amdgcn_sched_barrier(0);
  if (threadIdx.x == 0) {
    unsigned g = __hip_atomic_load(&bar[0], __ATOMIC_RELAXED, __HIP_MEMORY_SCOPE_AGENT);
    unsigned cnt = __hip_atomic_fetch_add(&bar[32], 1u, __ATOMIC_RELAXED, __HIP_MEMORY_SCOPE_AGENT);
    if (cnt == (unsigned)(NBLK-1)) {
      __hip_atomic_store(&bar[32], 0u, __ATOMIC_RELAXED, __HIP_MEMORY_SCOPE_AGENT);
      asm volatile("s_waitcnt vmcnt(0)" ::: "memory");
      __hip_atomic_store(&bar[0], g+1u, __ATOMIC_RELAXED, __HIP_MEMORY_SCOPE_AGENT);
    } else {
      unsigned cur;
      do { __builtin_amdgcn_s_sleep(1);
           cur = __hip_atomic_load(&bar[0], __ATOMIC_RELAXED, __HIP_MEMORY_SCOPE_AGENT);
      } while (cur == g);
    }
  }
  __builtin_amdgcn_sched_barrier(0);
  __builtin_amdgcn_s_barrier();
  __builtin_amdgcn_sched_barrier(0);
  asm volatile("" ::: "memory");
}

// ---------------- K1 (round-7 verbatim, proven)
__global__ __launch_bounds__(320) void k1_mfma(
    const float* __restrict__ x, const float* __restrict__ w1,
    float* __restrict__ G1, unsigned* __restrict__ bar)
{
  const int tid = threadIdx.x;
  if (blockIdx.x == 0 && tid == 0) {
    __hip_atomic_store(&bar[0], 0u, __ATOMIC_RELAXED, __HIP_MEMORY_SCOPE_AGENT);
    __hip_atomic_store(&bar[32], 0u, __ATOMIC_RELAXED, __HIP_MEMORY_SCOPE_AGENT);
  }
  __shared__ unsigned short WhL[2][RPB1*WSTR], WlL[2][RPB1*WSTR];
  __shared__ unsigned short XhL[2][80*WSTR],  XlL[2][80*WSTR];

  const int rb = blockIdx.x % RB1;
  const int ks = blockIdx.x / RB1;
  const int r0 = rb * RPB1;
  const int kofs = ks * KSL1;
  const int wv_ = tid >> 6;
  const int lane = tid & 63;
  const int p = lane & 15;
  const int q = lane >> 4;

  f32x4 acc[3][5];
  #pragma unroll
  for (int rt = 0; rt < 3; ++rt)
    #pragma unroll
    for (int mt = 0; mt < 5; ++mt) acc[rt][mt] = (f32x4){0.f,0.f,0.f,0.f};

  float4 wr[6], xrg[2];

  #define ISSUE_STAGE(cc)                                                      \
    { const int kbase = kofs + (cc)*32;                                        \
      _Pragma("unroll")                                                        \
      for (int u = 0; u < 6; ++u) {                                            \
        const int idx = tid + u*320;                                           \
        const int row = idx >> 3, k4 = idx & 7;                                \
        wr[u] = *(const float4*)(w1 + (size_t)(r0+row)*Fn + kbase + k4*4);     \
      }                                                                        \
      _Pragma("unroll")                                                        \
      for (int u = 0; u < 2; ++u) {                                            \
        const int idx = tid + u*320;                                           \
        const int mrow = idx >> 3, k4 = idx & 7;                               \
        xrg[u] = (mrow < Mn)                                                   \
          ? *(const float4*)(x + (size_t)mrow*Fn + kbase + k4*4)               \
          : make_float4(0.f,0.f,0.f,0.f);                                      \
      }                                                                        \
    }

  #define CVTW(dsth, dstl, off, v)                                             \
    { const unsigned short h0=f2bf(v.x), h1=f2bf(v.y), h2=f2bf(v.z), h3=f2bf(v.w); \
      const unsigned short l0=f2bf(v.x-bf2f(h0)), l1=f2bf(v.y-bf2f(h1));       \
      const unsigned short l2=f2bf(v.z-bf2f(h2)), l3=f2bf(v.w-bf2f(h3));       \
      *(uint2*)&dsth[off] = make_uint2((unsigned)h0|((unsigned)h1<<16),        \
                                       (unsigned)h2|((unsigned)h3<<16));       \
      *(uint2*)&dstl[off] = make_uint2((unsigned)l0|((unsigned)l1<<16),        \
                                       (unsigned)l2|((unsigned)l3<<16));       \
    }

  #define WRITE_STAGE(bb)                                                     \
    { _Pragma("unroll")                                                       \
      for (int u = 0; u < 6; ++u) {                                           \
        const int idx = tid + u*320;                                          \
        const int row = idx >> 3, k4 = idx & 7;                               \
        CVTW(WhL[bb], WlL[bb], row*WSTR + k4*4, wr[u]);                       \
      }                                                                       \
      _Pragma("unroll")                                                       \
      for (int u = 0; u < 2; ++u) {                                           \
        const int idx = tid + u*320;                                          \
        const int mrow = idx >> 3, k4 = idx & 7;                              \
        CVTW(XhL[bb], XlL[bb], mrow*WSTR + k4*4, xrg[u]);                     \
      }                                                                       \
    }

  ISSUE_STAGE(0);
  WRITE_STAGE(0);
  __syncthreads();

  for (int c = 0; c < NC1; ++c) {
    const int buf = c & 1;
    if (c+1 < NC1) ISSUE_STAGE(c+1);

    bf16x8 Bh[5], Bl[5];
    #pragma unroll
    for (int mt = 0; mt < 5; ++mt) {
      const int moff = (mt*16 + p)*WSTR + q*8;
      Bh[mt] = *(const bf16x8*)&XhL[buf][moff];
      Bl[mt] = *(const bf16x8*)&XlL[buf][moff];
    }
    #pragma unroll
    for (int rt = 0; rt < 3; ++rt) {
      const int roff = ((wv_ + 5*rt)*16 + p)*WSTR + q*8;
      const bf16x8 Ah = *(const bf16x8*)&WhL[buf][roff];
      const bf16x8 Al = *(const bf16x8*)&WlL[buf][roff];
      #pragma unroll
      for (int mt = 0; mt < 5; ++mt) {
        acc[rt][mt] = __builtin_amdgcn_mfma_f32_16x16x32_bf16(Ah, Bh[mt], acc[rt][mt], 0, 0, 0);
        acc[rt][mt] = __builtin_amdgcn_mfma_f32_16x16x32_bf16(Ah, Bl[mt], acc[rt][mt], 0, 0, 0);
        acc[rt][mt] = __builtin_amdgcn_mfma_f32_16x16x32_bf16(Al, Bh[mt], acc[rt][mt], 0, 0, 0);
      }
    }

    if (c+1 < NC1) WRITE_STAGE(buf^1);
    __syncthreads();
  }

  #pragma unroll
  for (int rt = 0; rt < 3; ++rt)
    #pragma unroll
    for (int mt = 0; mt < 5; ++mt) {
      const int m = mt*16 + p;
      if (m < Mn) {
        #pragma unroll
        for (int r4 = 0; r4 < 4; ++r4) {
          const int grow = r0 + (wv_ + 5*rt)*16 + q*4 + r4;
          atomicAdd(&G1[(size_t)grow*Mn + m], acc[rt][mt][r4]);
        }
      }
    }
  #undef ISSUE_STAGE
  #undef WRITE_STAGE
  #undef CVTW
}

// ---------------- K2 (cooperative, 225 x 512): L1 step i ∥ L2 step i-1.
// Steady path: NO LDS h-staging (per-lane direct global slices), raw barriers,
// partial-drain grid barrier -> weight prefetch flies across the whole interval.
__global__ __launch_bounds__(512) void k_rec(
    const float* __restrict__ G1, float* __restrict__ out1, float* __restrict__ h2arr,
    const float* __restrict__ whh1,
    const float* __restrict__ wih2, const float* __restrict__ whh2,
    const float* __restrict__ bih2, const float* __restrict__ bhh2,
    const float* __restrict__ bih1, const float* __restrict__ bhh1,
    const float* __restrict__ wobj1, const float* __restrict__ bobj1,
    const float* __restrict__ wrel,  const float* __restrict__ brel,
    const float* __restrict__ wobj2, const float* __restrict__ bobj2,
    const float* __restrict__ embed, float* __restrict__ dout,
    unsigned* __restrict__ bar)
{
  __shared__ float hls[Bn][904];    // tail staging only
  __shared__ float h2l[Bn][904];
  __shared__ float wvls[Bn][104];
  __shared__ float gls[16][68];
  __shared__ float bls[SEQn][16];
  __shared__ float gexA[16][Bn], gexB[16][Bn];
  __shared__ float cA[4][Bn], cB[4][Bn];
  __shared__ float red[4];
  __shared__ int idxls[Bn];

  const int tid = threadIdx.x;
  const int blk = blockIdx.x;
  const int j0 = blk * 4;
  const int wv_ = tid >> 6;
  const int lane = tid & 63;

  if (tid < 8) {
    const int jj = tid >> 1, m = tid & 1;
    cA[jj][m] = 0.f; cB[jj][m] = 0.f;
    gstore(h2arr + ((size_t)0*Bn + m)*Hn + j0 + jj, 0.f);  // slot 0
  }

  for (int qq = tid; qq < 16*Mn; qq += 512) {
    const int rho = qq / Mn, t = qq % Mn;
    const int gate = rho >> 2, jj = rho & 3;
    const size_t rA = (size_t)gate*Hn + j0 + jj;
    gls[rho][t] = G1[rA*Mn + t] + bih1[rA] + bhh1[rA];
  }
  for (int qq = tid; qq < SEQn*16; qq += 512) {
    const int s = qq / 16, rho = qq % 16;
    const int gate = rho >> 2, jj = rho & 3;
    const size_t ro = (size_t)s*G4n + (size_t)gate*Hn + j0 + jj;
    bls[s][rho] = bih2[ro] + bhh2[ro];
  }

  float4 wAreg[2][4];
  #pragma unroll
  for (int ri = 0; ri < 2; ++ri) {
    const int rho = wv_*2 + ri;
    const int gate = rho >> 2, jj = rho & 3;
    const size_t row = (size_t)gate*Hn + j0 + jj;
    #pragma unroll
    for (int e = 0; e < 4; ++e) {
      const int k = lane*4 + e*256;
      wAreg[ri][e] = (k <= Hn-4) ? *(const float4*)(whh1 + row*Hn + k)
                                 : make_float4(0.f,0.f,0.f,0.f);
    }
  }

  // single-buffer L2 weight prefetch registers
  float4 wiR[2][4], whR[2][4];
  #define ISSUE_W(sp, KMX)                                                   \
    { _Pragma("unroll")                                                      \
      for (int ri = 0; ri < 2; ++ri) {                                       \
        const int rho = wv_*2 + ri;                                          \
        const int gate = rho >> 2, jj = rho & 3;                             \
        const size_t ro = (size_t)(sp)*G4n + (size_t)gate*Hn + j0 + jj;      \
        const float* wI = wih2 + ro*1000;                                    \
        const float* wH = whh2 + ro*Hn;                                      \
        _Pragma("unroll")                                                    \
        for (int e = 0; e < 4; ++e) {                                        \
          const int k = lane*4 + e*256;                                      \
          if (k <= (KMX)) wiR[ri][e] = *(const float4*)(wI + k);             \
          if (k <= 896)   whR[ri][e] = *(const float4*)(wH + k);             \
        }                                                                    \
      }                                                                      \
    }

  #define UPD_A(ivar)                                                        \
    { const float cc = sigf(gexA[4+jj][m])*cA[jj][m]                         \
                     + sigf(gexA[jj][m])*tanhf(gexA[8+jj][m]);               \
      cA[jj][m] = cc;                                                        \
      gstore(out1 + ((size_t)(ivar)*Bn + m)*Hn + j0 + jj,                    \
             sigf(gexA[12+jj][m])*tanhf(cc)); }

  #define UPD_B(svar)                                                        \
    { const float cc = sigf(gexB[4+jj][m])*cB[jj][m]                         \
                     + sigf(gexB[jj][m])*tanhf(gexB[8+jj][m]);               \
      cB[jj][m] = cc;                                                        \
      gstore(h2arr + ((size_t)((svar)+1)*Bn + m)*Hn + j0 + jj,               \
             sigf(gexB[12+jj][m])*tanhf(cc)); }

  ISSUE_W(0, 896);
  __syncthreads();            // gls/bls ready (drains W(0) once — prologue only)

  // ---- interval 0: A step 0 (h_prev = 0)
  if (lane == 0) {
    #pragma unroll
    for (int ri = 0; ri < 2; ++ri) {
      const int rho = wv_*2 + ri;
      gexA[rho][0] = gls[rho][0];
      gexA[rho][1] = gls[rho][1];
    }
  }
  __syncthreads();
  if (tid < 8) { const int jj = tid >> 1, m = tid & 1; UPD_A(0); }
  gbar(bar);

  // ---- steady intervals 1..31
  for (int iv = 1; iv <= 31; ++iv) {
    const int s = iv - 1;
    // per-lane h slices, direct from global (write-once addresses -> coherent)
    float4 hv[2][4], h2v[2][4];
    #pragma unroll
    for (int e = 0; e < 4; ++e) {
      const int k = lane*4 + e*256;
      #pragma unroll
      for (int m = 0; m < 2; ++m) {
        hv[m][e]  = (k <= 896) ? *(const float4*)(out1  + ((size_t)s*Bn + m)*Hn + k)
                               : make_float4(0.f,0.f,0.f,0.f);
        h2v[m][e] = (k <= 896) ? *(const float4*)(h2arr + ((size_t)s*Bn + m)*Hn + k)
                               : make_float4(0.f,0.f,0.f,0.f);
      }
    }
    // A-dots + B-dots (all in registers)
    #pragma unroll
    for (int ri = 0; ri < 2; ++ri) {
      const int rho = wv_*2 + ri;
      float a0=0.f, a1=0.f, b0=0.f, b1=0.f;
      #pragma unroll
      for (int e = 0; e < 4; ++e) {
        const int k = lane*4 + e*256;
        if (k <= 896) {
          a0 += dot4(wAreg[ri][e], hv[0][e]);  a1 += dot4(wAreg[ri][e], hv[1][e]);
          b0 += dot4(wiR[ri][e],   hv[0][e]);  b1 += dot4(wiR[ri][e],   hv[1][e]);
          b0 += dot4(whR[ri][e],  h2v[0][e]);  b1 += dot4(whR[ri][e],  h2v[1][e]);
        }
      }
      a0 = wred(a0); a1 = wred(a1); b0 = wred(b0); b1 = wred(b1);
      if (lane == 0) {
        gexA[rho][0] = a0 + gls[rho][iv*Bn + 0];
        gexA[rho][1] = a1 + gls[rho][iv*Bn + 1];
        const float bb = bls[s][rho];
        gexB[rho][0] = b0 + bb;
        gexB[rho][1] = b1 + bb;
      }
    }
    asm volatile("s_waitcnt lgkmcnt(0)" ::: "memory");
    __builtin_amdgcn_sched_barrier(0);
    // prefetch next step's weights — fly through update + grid barrier + next h-loads
    ISSUE_W(iv, (iv >= 31) ? 996 : 896);
    __builtin_amdgcn_sched_barrier(0);
    __builtin_amdgcn_s_barrier();          // gex visible block-wide
    __builtin_amdgcn_sched_barrier(0);
    if (tid < 8) {
      const int jj = tid >> 1, m = tid & 1;
      UPD_A(iv);
      UPD_B(s);
    }
    gbar_lite(bar, wv_);
  }

  // ---- tail: i = 32..36 (full-drain barriers, LDS staging — proven path)
  for (int i = 32; i < 37; ++i) {
    if (i == 33 || i == 35) {        // argmax + word vector
      if (wv_ < 2) {
        const int m = wv_;
        const int nout = (i == 33) ? OBJn : RELn;
        const int off = (i == 33) ? 0 : Bn*OBJn;
        float v = -1e30f; int idx = 0;
        for (int o = lane; o < nout; o += 64) {
          float t = gload(dout + off + m*nout + o);
          if (t > v) { v = t; idx = o; }
        }
        #pragma unroll
        for (int d = 32; d >= 1; d >>= 1) {
          float ov = __shfl_xor(v, d, 64);
          int   oi = __shfl_xor(idx, d, 64);
          if (ov > v || (ov == v && oi < idx)) { v = ov; idx = oi; }
        }
        if (lane == 0) idxls[m] = idx + ((i == 35) ? OBJn : 0);
      }
      __syncthreads();
      for (int qq = tid; qq < Bn*104; qq += 512) {
        const int m = qq / 104, v4 = qq % 104;
        wvls[m][v4] = (v4 < WVn) ? embed[(size_t)idxls[m]*WVn + v4] : 0.f;
      }
      __syncthreads();
    }

    const bool hasA = (i == 32);
    const int  s = (i == 33) ? 31 : (i == 35) ? 32 : -1;
    const bool hasB = (s >= 0);
    const int  srcA = (i == 35) ? 32 : i-1;

    if (hasA || i == 35) {
      for (int qq = tid; qq < 1808; qq += 512) {
        const int m = qq / 904, kk = qq % 904;
        hls[m][kk] = (kk < 900)
          ? gload(out1 + ((size_t)srcA*Bn + m)*Hn + kk) : 0.f;
      }
    }
    if (hasB) {
      for (int qq = tid; qq < 1808; qq += 512) {
        const int m = qq / 904, kk = qq % 904;
        h2l[m][kk] = (kk < 900)
          ? gload(h2arr + ((size_t)s*Bn + m)*Hn + kk) : 0.f;
      }
    }
    __syncthreads();

    if (hasA) {
      #pragma unroll
      for (int ri = 0; ri < 2; ++ri) {
        const int rho = wv_*2 + ri;
        float a0 = 0.f, a1 = 0.f;
        #pragma unroll
        for (int e = 0; e < 4; ++e) {
          const int k = lane*4 + e*256;
          if (k <= Hn-4) {
            a0 += dot4(wAreg[ri][e], *(const float4*)&hls[0][k]);
            a1 += dot4(wAreg[ri][e], *(const float4*)&hls[1][k]);
          }
        }
        a0 = wred(a0); a1 = wred(a1);
        if (lane == 0) {
          gexA[rho][0] = a0 + gls[rho][32*Bn + 0];
          gexA[rho][1] = a1 + gls[rho][32*Bn + 1];
        }
      }
    }

    if (hasB) {
      #pragma unroll
      for (int ri = 0; ri < 2; ++ri) {
        const int rho = wv_*2 + ri;
        float b0 = 0.f, b1 = 0.f;
        #pragma unroll
        for (int e = 0; e < 4; ++e) {
          const int k = lane*4 + e*256;
          if (k <= 896) {
            b0 += dot4(wiR[ri][e], *(const float4*)&hls[0][k]);
            b1 += dot4(wiR[ri][e], *(const float4*)&hls[1][k]);
            b0 += dot4(whR[ri][e], *(const float4*)&h2l[0][k]);
            b1 += dot4(whR[ri][e], *(const float4*)&h2l[1][k]);
          } else if (k >= 900 && k <= 996) {
            b0 += dot4(wiR[ri][e], *(const float4*)&wvls[0][k-900]);
            b1 += dot4(wiR[ri][e], *(const float4*)&wvls[1][k-900]);
          }
        }
        b0 = wred(b0); b1 = wred(b1);
        if (lane == 0) {
          const float bb = bls[s][rho];
          gexB[rho][0] = b0 + bb;
          gexB[rho][1] = b1 + bb;
        }
      }
      if (i == 33) ISSUE_W(32, 996);   // consumed at i=35
    }

    if (i == 32 || i == 34 || i == 36) {   // heads: obj1 / rel / obj2
      const int nout = (i == 34) ? RELn : OBJn;
      const float* wh  = (i == 32) ? wobj1 : (i == 34) ? wrel : wobj2;
      const float* bh_ = (i == 32) ? bobj1 : (i == 34) ? brel : bobj2;
      const int off = (i == 32) ? 0 : (i == 34) ? (Bn*OBJn) : (Bn*OBJn + Bn*RELn);
      const int hb = (i == 32) ? 31 : (i == 34) ? 32 : 33;
      if (blk < nout*Bn) {
        const int o = blk >> 1, m = blk & 1;
        float p = 0.f;
        if (tid < 225) {
          const float4 wv4 = *(const float4*)(wh + (size_t)o*Hn + tid*4);
          const float* hp = h2arr + ((size_t)hb*Bn + m)*Hn + tid*4;
          p = wv4.x*gload(hp+0) + wv4.y*gload(hp+1)
            + wv4.z*gload(hp+2) + wv4.w*gload(hp+3);
        }
        if (wv_ < 4) {
          const float pr = wred(p);
          if (lane == 0) red[wv_] = pr;
        }
        __syncthreads();
        if (tid == 0)
          gstore(&dout[off + m*nout + o], red[0]+red[1]+red[2]+red[3] + bh_[o]);
      }
    }

    __syncthreads();
    if (tid < 8) {
      const int jj = tid >> 1, m = tid & 1;
      if (hasA) UPD_A(32);
      if (i == 33) UPD_B(31);
      if (i == 35) UPD_B(32);
    }

    if (i < 36) gbar(bar);
  }
  #undef ISSUE_W
  #undef UPD_A
  #undef UPD_B
}

extern "C" void kernel_launch(void* const* d_in, const int* in_sizes, int n_in,
                              void* d_out, int out_size, void* d_ws, size_t ws_size,
                              hipStream_t stream)
{
  (void)in_sizes; (void)n_in; (void)out_size; (void)ws_size;
  const float* x     = (const float*)d_in[0];
  const float* wih1  = (const float*)d_in[1];
  const float* whh1  = (const float*)d_in[2];
  const float* bih1  = (const float*)d_in[3];
  const float* bhh1  = (const float*)d_in[4];
  const float* wih2  = (const float*)d_in[5];
  const float* whh2  = (const float*)d_in[6];
  const float* bih2  = (const float*)d_in[7];
  const float* bhh2  = (const float*)d_in[8];
  const float* wobj1 = (const float*)d_in[9];
  const float* bobj1 = (const float*)d_in[10];
  const float* wrel  = (const float*)d_in[11];
  const float* brel  = (const float*)d_in[12];
  const float* wobj2 = (const float*)d_in[13];
  const float* bobj2 = (const float*)d_in[14];
  const float* embed = (const float*)d_in[15];
  float* dout = (float*)d_out;

  float* ws = (float*)d_ws;
  float* G1    = ws;                                   // 3600*66
  float* out1  = G1 + (size_t)G4n*Mn;                  // 33*2*900
  float* h2arr = out1 + (size_t)SEQn*Bn*Hn;            // 34*2*900 (rotating slots)
  unsigned* bar = (unsigned*)(h2arr + (size_t)34*Bn*Hn);

  hipMemsetAsync(G1, 0, (size_t)G4n*Mn*sizeof(float), stream);
  hipLaunchKernelGGL(k1_mfma, dim3(RB1*KS1), dim3(320), 0, stream, x, wih1, G1, bar);

  void* args[19];
  args[0]  = (void*)&G1;    args[1]  = (void*)&out1;  args[2]  = (void*)&h2arr;
  args[3]  = (void*)&whh1;  args[4]  = (void*)&wih2;  args[5]  = (void*)&whh2;
  args[6]  = (void*)&bih2;  args[7]  = (void*)&bhh2;  args[8]  = (void*)&bih1;
  args[9]  = (void*)&bhh1;  args[10] = (void*)&wobj1; args[11] = (void*)&bobj1;
  args[12] = (void*)&wrel;  args[13] = (void*)&brel;  args[14] = (void*)&wobj2;
  args[15] = (void*)&bobj2; args[16] = (void*)&embed; args[17] = (void*)&dout;
  args[18] = (void*)&bar;
  hipLaunchCooperativeKernel((void*)k_rec, dim3(NBLK), dim3(512), args, 0, stream);
}

// Round 11
// 475.654 us; speedup vs baseline: 1.4196x; 1.0516x over previous
//
#include <hip/hip_runtime.h>

#define SEQn 33
#define Fn   20480
#define Hn   900
#define Bn   2
#define WVn  100
#define OBJn 35
#define RELn 82
#define G4n  3600
#define Mn   66
#define NBLK 225

// ---- K1 MFMA geometry: 144 rows/block, 192 thr, 2 blocks/CU
#define KS1  16
#define KSL1 (Fn/KS1)      // 1280
#define RB1  25
#define RPB1 144
#define NC1  (KSL1/32)     // 40
#define WSTR 40
#define THR1 192

typedef __attribute__((ext_vector_type(8))) short bf16x8;
typedef __attribute__((ext_vector_type(4))) float f32x4;

__device__ __forceinline__ float sigf(float v){ return 1.f/(1.f+expf(-v)); }
__device__ __forceinline__ float dot4(float4 a, float4 b){ return a.x*b.x+a.y*b.y+a.z*b.z+a.w*b.w; }
__device__ __forceinline__ float wred(float v){
  #pragma unroll
  for (int d = 32; d >= 1; d >>= 1) v += __shfl_xor(v, d, 64);
  return v;
}
__device__ __forceinline__ float gload(const float* p){
  return __hip_atomic_load((const float*)p, __ATOMIC_RELAXED, __HIP_MEMORY_SCOPE_AGENT);
}
__device__ __forceinline__ void gstore(float* p, float v){
  __hip_atomic_store(p, v, __ATOMIC_RELAXED, __HIP_MEMORY_SCOPE_AGENT);
}
__device__ __forceinline__ unsigned short f2bf(float f){
  unsigned u = __float_as_uint(f);
  unsigned r = u + 0x7FFFu + ((u >> 16) & 1u);
  return (unsigned short)(r >> 16);
}
__device__ __forceinline__ float bf2f(unsigned short h){
  return __uint_as_float(((unsigned)h) << 16);
}

// two-level arrival tree: 8 group counters (own 64B lines) + level-2 + generation.
// bar[0]=gen, bar[16]=L2 count, bar[32+g*16]=group g count. Thread 0 only.
__device__ __forceinline__ void arrive_and_wait(unsigned* bar){
  unsigned g = __hip_atomic_load(&bar[0], __ATOMIC_RELAXED, __HIP_MEMORY_SCOPE_AGENT);
  const unsigned grp = (unsigned)blockIdx.x & 7u;
  const unsigned gsz = (grp == 0u) ? 29u : 28u;     // 225 = 29 + 7*28
  unsigned c = __hip_atomic_fetch_add(&bar[32 + grp*16], 1u, __ATOMIC_RELAXED, __HIP_MEMORY_SCOPE_AGENT);
  if (c == gsz - 1u) {
    unsigned c2 = __hip_atomic_fetch_add(&bar[16], 1u, __ATOMIC_RELAXED, __HIP_MEMORY_SCOPE_AGENT);
    if (c2 == 7u) {
      __hip_atomic_store(&bar[16], 0u, __ATOMIC_RELAXED, __HIP_MEMORY_SCOPE_AGENT);
      #pragma unroll
      for (int g8 = 0; g8 < 8; ++g8)
        __hip_atomic_store(&bar[32 + g8*16], 0u, __ATOMIC_RELAXED, __HIP_MEMORY_SCOPE_AGENT);
      asm volatile("s_waitcnt vmcnt(0)" ::: "memory");   // resets at IC before gen bump
      __hip_atomic_store(&bar[0], g + 1u, __ATOMIC_RELAXED, __HIP_MEMORY_SCOPE_AGENT);
      return;
    }
  }
  unsigned cur;
  do { __builtin_amdgcn_s_sleep(1);
       cur = __hip_atomic_load(&bar[0], __ATOMIC_RELAXED, __HIP_MEMORY_SCOPE_AGENT);
  } while (cur == g);
}

// full-drain grid barrier — i=0 and tail
__device__ __forceinline__ void gbar(unsigned* bar){
  __syncthreads();
  if (threadIdx.x == 0) arrive_and_wait(bar);
  __syncthreads();
}

// partial-drain grid barrier: only wave 0 (sole global-storing wave) drains vmcnt,
// so other waves' in-flight weight prefetch loads survive the barrier.
__device__ __forceinline__ void gbar_lite(unsigned* bar, int wv){
  asm volatile("" ::: "memory");
  if (wv == 0) asm volatile("s_waitcnt vmcnt(0)" ::: "memory");
  __builtin_amdgcn_sched_barrier(0);
  __builtin_amdgcn_s_barrier();
  __builtin_amdgcn_sched_barrier(0);
  if (threadIdx.x == 0) arrive_and_wait(bar);
  __builtin_amdgcn_sched_barrier(0);
  __builtin_amdgcn_s_barrier();
  __builtin_amdgcn_sched_barrier(0);
  asm volatile("" ::: "memory");
}

// ---------------- K1 (MFMA split-precision bf16, 2 blocks/CU geometry)
__global__ __launch_bounds__(THR1) void k1_mfma(
    const float* __restrict__ x, const float* __restrict__ w1,
    float* __restrict__ G1, unsigned* __restrict__ bar)
{
  const int tid = threadIdx.x;
  if (blockIdx.x == 0 && tid < 10) {     // init barrier words for k_rec
    if (tid == 0) __hip_atomic_store(&bar[0], 0u, __ATOMIC_RELAXED, __HIP_MEMORY_SCOPE_AGENT);
    else if (tid == 1) __hip_atomic_store(&bar[16], 0u, __ATOMIC_RELAXED, __HIP_MEMORY_SCOPE_AGENT);
    else __hip_atomic_store(&bar[32 + (tid-2)*16], 0u, __ATOMIC_RELAXED, __HIP_MEMORY_SCOPE_AGENT);
  }
  __shared__ unsigned short WhL[2][RPB1*WSTR], WlL[2][RPB1*WSTR];
  __shared__ unsigned short XhL[2][80*WSTR],  XlL[2][80*WSTR];

  const int rb = blockIdx.x % RB1;
  const int ks = blockIdx.x / RB1;
  const int r0 = rb * RPB1;
  const int kofs = ks * KSL1;
  const int wv_ = tid >> 6;        // 0..2
  const int lane = tid & 63;
  const int p = lane & 15;
  const int q = lane >> 4;

  f32x4 acc[3][5];
  #pragma unroll
  for (int rt = 0; rt < 3; ++rt)
    #pragma unroll
    for (int mt = 0; mt < 5; ++mt) acc[rt][mt] = (f32x4){0.f,0.f,0.f,0.f};

  float4 wr[6], xrg[4];

  #define ISSUE_STAGE(cc)                                                      \
    { const int kbase = kofs + (cc)*32;                                        \
      _Pragma("unroll")                                                        \
      for (int u = 0; u < 6; ++u) {                                            \
        const int idx = tid + u*THR1;                                          \
        const int row = idx >> 3, k4 = idx & 7;                                \
        wr[u] = *(const float4*)(w1 + (size_t)(r0+row)*Fn + kbase + k4*4);     \
      }                                                                        \
      _Pragma("unroll")                                                        \
      for (int u = 0; u < 4; ++u) {                                            \
        const int idx = tid + u*THR1;                                          \
        const int mrow = idx >> 3, k4 = idx & 7;                               \
        xrg[u] = (idx < 640 && mrow < Mn)                                      \
          ? *(const float4*)(x + (size_t)mrow*Fn + kbase + k4*4)               \
          : make_float4(0.f,0.f,0.f,0.f);                                      \
      }                                                                        \
    }

  #define CVTW(dsth, dstl, off, v)                                             \
    { const unsigned short h0=f2bf(v.x), h1=f2bf(v.y), h2=f2bf(v.z), h3=f2bf(v.w); \
      const unsigned short l0=f2bf(v.x-bf2f(h0)), l1=f2bf(v.y-bf2f(h1));       \
      const unsigned short l2=f2bf(v.z-bf2f(h2)), l3=f2bf(v.w-bf2f(h3));       \
      *(uint2*)&dsth[off] = make_uint2((unsigned)h0|((unsigned)h1<<16),        \
                                       (unsigned)h2|((unsigned)h3<<16));       \
      *(uint2*)&dstl[off] = make_uint2((unsigned)l0|((unsigned)l1<<16),        \
                                       (unsigned)l2|((unsigned)l3<<16));       \
    }

  #define WRITE_STAGE(bb)                                                     \
    { _Pragma("unroll")                                                       \
      for (int u = 0; u < 6; ++u) {                                           \
        const int idx = tid + u*THR1;                                         \
        const int row = idx >> 3, k4 = idx & 7;                               \
        CVTW(WhL[bb], WlL[bb], row*WSTR + k4*4, wr[u]);                       \
      }                                                                       \
      _Pragma("unroll")                                                       \
      for (int u = 0; u < 4; ++u) {                                           \
        const int idx = tid + u*THR1;                                         \
        if (idx < 640) {                                                      \
          const int mrow = idx >> 3, k4 = idx & 7;                            \
          CVTW(XhL[bb], XlL[bb], mrow*WSTR + k4*4, xrg[u]);                   \
        }                                                                     \
      }                                                                       \
    }

  ISSUE_STAGE(0);
  WRITE_STAGE(0);
  __syncthreads();

  for (int c = 0; c < NC1; ++c) {
    const int buf = c & 1;
    if (c+1 < NC1) ISSUE_STAGE(c+1);

    bf16x8 Bh[5], Bl[5];
    #pragma unroll
    for (int mt = 0; mt < 5; ++mt) {
      const int moff = (mt*16 + p)*WSTR + q*8;
      Bh[mt] = *(const bf16x8*)&XhL[buf][moff];
      Bl[mt] = *(const bf16x8*)&XlL[buf][moff];
    }
    #pragma unroll
    for (int rt = 0; rt < 3; ++rt) {
      const int roff = ((wv_ + 3*rt)*16 + p)*WSTR + q*8;
      const bf16x8 Ah = *(const bf16x8*)&WhL[buf][roff];
      const bf16x8 Al = *(const bf16x8*)&WlL[buf][roff];
      #pragma unroll
      for (int mt = 0; mt < 5; ++mt) {
        acc[rt][mt] = __builtin_amdgcn_mfma_f32_16x16x32_bf16(Ah, Bh[mt], acc[rt][mt], 0, 0, 0);
        acc[rt][mt] = __builtin_amdgcn_mfma_f32_16x16x32_bf16(Ah, Bl[mt], acc[rt][mt], 0, 0, 0);
        acc[rt][mt] = __builtin_amdgcn_mfma_f32_16x16x32_bf16(Al, Bh[mt], acc[rt][mt], 0, 0, 0);
      }
    }

    if (c+1 < NC1) WRITE_STAGE(buf^1);
    __syncthreads();
  }

  #pragma unroll
  for (int rt = 0; rt < 3; ++rt)
    #pragma unroll
    for (int mt = 0; mt < 5; ++mt) {
      const int m = mt*16 + p;
      if (m < Mn) {
        #pragma unroll
        for (int r4 = 0; r4 < 4; ++r4) {
          const int grow = r0 + (wv_ + 3*rt)*16 + q*4 + r4;
          atomicAdd(&G1[(size_t)grow*Mn + m], acc[rt][mt][r4]);
        }
      }
    }
  #undef ISSUE_STAGE
  #undef WRITE_STAGE
  #undef CVTW
}

// ---------------- K2 (cooperative, 225 x 512) — round-10 structure, tree barrier
__global__ __launch_bounds__(512) void k_rec(
    const float* __restrict__ G1, float* __restrict__ out1, float* __restrict__ h2arr,
    const float* __restrict__ whh1,
    const float* __restrict__ wih2, const float* __restrict__ whh2,
    const float* __restrict__ bih2, const float* __restrict__ bhh2,
    const float* __restrict__ bih1, const float* __restrict__ bhh1,
    const float* __restrict__ wobj1, const float* __restrict__ bobj1,
    const float* __restrict__ wrel,  const float* __restrict__ brel,
    const float* __restrict__ wobj2, const float* __restrict__ bobj2,
    const float* __restrict__ embed, float* __restrict__ dout,
    unsigned* __restrict__ bar)
{
  __shared__ float hls[Bn][904];    // tail staging only
  __shared__ float h2l[Bn][904];
  __shared__ float wvls[Bn][104];
  __shared__ float gls[16][68];
  __shared__ float bls[SEQn][16];
  __shared__ float gexA[16][Bn], gexB[16][Bn];
  __shared__ float cA[4][Bn], cB[4][Bn];
  __shared__ float red[4];
  __shared__ int idxls[Bn];

  const int tid = threadIdx.x;
  const int blk = blockIdx.x;
  const int j0 = blk * 4;
  const int wv_ = tid >> 6;
  const int lane = tid & 63;

  if (tid < 8) {
    const int jj = tid >> 1, m = tid & 1;
    cA[jj][m] = 0.f; cB[jj][m] = 0.f;
    gstore(h2arr + ((size_t)0*Bn + m)*Hn + j0 + jj, 0.f);  // slot 0
  }

  for (int qq = tid; qq < 16*Mn; qq += 512) {
    const int rho = qq / Mn, t = qq % Mn;
    const int gate = rho >> 2, jj = rho & 3;
    const size_t rA = (size_t)gate*Hn + j0 + jj;
    gls[rho][t] = G1[rA*Mn + t] + bih1[rA] + bhh1[rA];
  }
  for (int qq = tid; qq < SEQn*16; qq += 512) {
    const int s = qq / 16, rho = qq % 16;
    const int gate = rho >> 2, jj = rho & 3;
    const size_t ro = (size_t)s*G4n + (size_t)gate*Hn + j0 + jj;
    bls[s][rho] = bih2[ro] + bhh2[ro];
  }

  float4 wAreg[2][4];
  #pragma unroll
  for (int ri = 0; ri < 2; ++ri) {
    const int rho = wv_*2 + ri;
    const int gate = rho >> 2, jj = rho & 3;
    const size_t row = (size_t)gate*Hn + j0 + jj;
    #pragma unroll
    for (int e = 0; e < 4; ++e) {
      const int k = lane*4 + e*256;
      wAreg[ri][e] = (k <= Hn-4) ? *(const float4*)(whh1 + row*Hn + k)
                                 : make_float4(0.f,0.f,0.f,0.f);
    }
  }

  // single-buffer L2 weight prefetch registers
  float4 wiR[2][4], whR[2][4];
  #define ISSUE_W(sp, KMX)                                                   \
    { _Pragma("unroll")                                                      \
      for (int ri = 0; ri < 2; ++ri) {                                       \
        const int rho = wv_*2 + ri;                                          \
        const int gate = rho >> 2, jj = rho & 3;                             \
        const size_t ro = (size_t)(sp)*G4n + (size_t)gate*Hn + j0 + jj;      \
        const float* wI = wih2 + ro*1000;                                    \
        const float* wH = whh2 + ro*Hn;                                      \
        _Pragma("unroll")                                                    \
        for (int e = 0; e < 4; ++e) {                                        \
          const int k = lane*4 + e*256;                                      \
          if (k <= (KMX)) wiR[ri][e] = *(const float4*)(wI + k);             \
          if (k <= 896)   whR[ri][e] = *(const float4*)(wH + k);             \
        }                                                                    \
      }                                                                      \
    }

  #define UPD_A(ivar)                                                        \
    { const float cc = sigf(gexA[4+jj][m])*cA[jj][m]                         \
                     + sigf(gexA[jj][m])*tanhf(gexA[8+jj][m]);               \
      cA[jj][m] = cc;                                                        \
      gstore(out1 + ((size_t)(ivar)*Bn + m)*Hn + j0 + jj,                    \
             sigf(gexA[12+jj][m])*tanhf(cc)); }

  #define UPD_B(svar)                                                        \
    { const float cc = sigf(gexB[4+jj][m])*cB[jj][m]                         \
                     + sigf(gexB[jj][m])*tanhf(gexB[8+jj][m]);               \
      cB[jj][m] = cc;                                                        \
      gstore(h2arr + ((size_t)((svar)+1)*Bn + m)*Hn + j0 + jj,               \
             sigf(gexB[12+jj][m])*tanhf(cc)); }

  ISSUE_W(0, 896);
  __syncthreads();            // gls/bls ready (drains W(0) once — prologue only)

  // ---- interval 0: A step 0 (h_prev = 0)
  if (lane == 0) {
    #pragma unroll
    for (int ri = 0; ri < 2; ++ri) {
      const int rho = wv_*2 + ri;
      gexA[rho][0] = gls[rho][0];
      gexA[rho][1] = gls[rho][1];
    }
  }
  __syncthreads();
  if (tid < 8) { const int jj = tid >> 1, m = tid & 1; UPD_A(0); }
  gbar(bar);

  // ---- steady intervals 1..31
  for (int iv = 1; iv <= 31; ++iv) {
    const int s = iv - 1;
    float4 hv[2][4], h2v[2][4];
    #pragma unroll
    for (int e = 0; e < 4; ++e) {
      const int k = lane*4 + e*256;
      #pragma unroll
      for (int m = 0; m < 2; ++m) {
        hv[m][e]  = (k <= 896) ? *(const float4*)(out1  + ((size_t)s*Bn + m)*Hn + k)
                               : make_float4(0.f,0.f,0.f,0.f);
        h2v[m][e] = (k <= 896) ? *(const float4*)(h2arr + ((size_t)s*Bn + m)*Hn + k)
                               : make_float4(0.f,0.f,0.f,0.f);
      }
    }
    #pragma unroll
    for (int ri = 0; ri < 2; ++ri) {
      const int rho = wv_*2 + ri;
      float a0=0.f, a1=0.f, b0=0.f, b1=0.f;
      #pragma unroll
      for (int e = 0; e < 4; ++e) {
        const int k = lane*4 + e*256;
        if (k <= 896) {
          a0 += dot4(wAreg[ri][e], hv[0][e]);  a1 += dot4(wAreg[ri][e], hv[1][e]);
          b0 += dot4(wiR[ri][e],   hv[0][e]);  b1 += dot4(wiR[ri][e],   hv[1][e]);
          b0 += dot4(whR[ri][e],  h2v[0][e]);  b1 += dot4(whR[ri][e],  h2v[1][e]);
        }
      }
      a0 = wred(a0); a1 = wred(a1); b0 = wred(b0); b1 = wred(b1);
      if (lane == 0) {
        gexA[rho][0] = a0 + gls[rho][iv*Bn + 0];
        gexA[rho][1] = a1 + gls[rho][iv*Bn + 1];
        const float bb = bls[s][rho];
        gexB[rho][0] = b0 + bb;
        gexB[rho][1] = b1 + bb;
      }
    }
    asm volatile("s_waitcnt lgkmcnt(0)" ::: "memory");
    __builtin_amdgcn_sched_barrier(0);
    ISSUE_W(iv, (iv >= 31) ? 996 : 896);    // prefetch flies across the grid barrier
    __builtin_amdgcn_sched_barrier(0);
    __builtin_amdgcn_s_barrier();           // gex visible block-wide
    __builtin_amdgcn_sched_barrier(0);
    if (tid < 8) {
      const int jj = tid >> 1, m = tid & 1;
      UPD_A(iv);
      UPD_B(s);
    }
    gbar_lite(bar, wv_);
  }

  // ---- tail: i = 32..36 (full-drain barriers, LDS staging — proven path)
  for (int i = 32; i < 37; ++i) {
    if (i == 33 || i == 35) {
      if (wv_ < 2) {
        const int m = wv_;
        const int nout = (i == 33) ? OBJn : RELn;
        const int off = (i == 33) ? 0 : Bn*OBJn;
        float v = -1e30f; int idx = 0;
        for (int o = lane; o < nout; o += 64) {
          float t = gload(dout + off + m*nout + o);
          if (t > v) { v = t; idx = o; }
        }
        #pragma unroll
        for (int d = 32; d >= 1; d >>= 1) {
          float ov = __shfl_xor(v, d, 64);
          int   oi = __shfl_xor(idx, d, 64);
          if (ov > v || (ov == v && oi < idx)) { v = ov; idx = oi; }
        }
        if (lane == 0) idxls[m] = idx + ((i == 35) ? OBJn : 0);
      }
      __syncthreads();
      for (int qq = tid; qq < Bn*104; qq += 512) {
        const int m = qq / 104, v4 = qq % 104;
        wvls[m][v4] = (v4 < WVn) ? embed[(size_t)idxls[m]*WVn + v4] : 0.f;
      }
      __syncthreads();
    }

    const bool hasA = (i == 32);
    const int  s = (i == 33) ? 31 : (i == 35) ? 32 : -1;
    const bool hasB = (s >= 0);
    const int  srcA = (i == 35) ? 32 : i-1;

    if (hasA || i == 35) {
      for (int qq = tid; qq < 1808; qq += 512) {
        const int m = qq / 904, kk = qq % 904;
        hls[m][kk] = (kk < 900)
          ? gload(out1 + ((size_t)srcA*Bn + m)*Hn + kk) : 0.f;
      }
    }
    if (hasB) {
      for (int qq = tid; qq < 1808; qq += 512) {
        const int m = qq / 904, kk = qq % 904;
        h2l[m][kk] = (kk < 900)
          ? gload(h2arr + ((size_t)s*Bn + m)*Hn + kk) : 0.f;
      }
    }
    __syncthreads();

    if (hasA) {
      #pragma unroll
      for (int ri = 0; ri < 2; ++ri) {
        const int rho = wv_*2 + ri;
        float a0 = 0.f, a1 = 0.f;
        #pragma unroll
        for (int e = 0; e < 4; ++e) {
          const int k = lane*4 + e*256;
          if (k <= Hn-4) {
            a0 += dot4(wAreg[ri][e], *(const float4*)&hls[0][k]);
            a1 += dot4(wAreg[ri][e], *(const float4*)&hls[1][k]);
          }
        }
        a0 = wred(a0); a1 = wred(a1);
        if (lane == 0) {
          gexA[rho][0] = a0 + gls[rho][32*Bn + 0];
          gexA[rho][1] = a1 + gls[rho][32*Bn + 1];
        }
      }
    }

    if (hasB) {
      #pragma unroll
      for (int ri = 0; ri < 2; ++ri) {
        const int rho = wv_*2 + ri;
        float b0 = 0.f, b1 = 0.f;
        #pragma unroll
        for (int e = 0; e < 4; ++e) {
          const int k = lane*4 + e*256;
          if (k <= 896) {
            b0 += dot4(wiR[ri][e], *(const float4*)&hls[0][k]);
            b1 += dot4(wiR[ri][e], *(const float4*)&hls[1][k]);
            b0 += dot4(whR[ri][e], *(const float4*)&h2l[0][k]);
            b1 += dot4(whR[ri][e], *(const float4*)&h2l[1][k]);
          } else if (k >= 900 && k <= 996) {
            b0 += dot4(wiR[ri][e], *(const float4*)&wvls[0][k-900]);
            b1 += dot4(wiR[ri][e], *(const float4*)&wvls[1][k-900]);
          }
        }
        b0 = wred(b0); b1 = wred(b1);
        if (lane == 0) {
          const float bb = bls[s][rho];
          gexB[rho][0] = b0 + bb;
          gexB[rho][1] = b1 + bb;
        }
      }
      if (i == 33) ISSUE_W(32, 996);   // consumed at i=35
    }

    if (i == 32 || i == 34 || i == 36) {
      const int nout = (i == 34) ? RELn : OBJn;
      const float* wh  = (i == 32) ? wobj1 : (i == 34) ? wrel : wobj2;
      const float* bh_ = (i == 32) ? bobj1 : (i == 34) ? brel : bobj2;
      const int off = (i == 32) ? 0 : (i == 34) ? (Bn*OBJn) : (Bn*OBJn + Bn*RELn);
      const int hb = (i == 32) ? 31 : (i == 34) ? 32 : 33;
      if (blk < nout*Bn) {
        const int o = blk >> 1, m = blk & 1;
        float p = 0.f;
        if (tid < 225) {
          const float4 wv4 = *(const float4*)(wh + (size_t)o*Hn + tid*4);
          const float* hp = h2arr + ((size_t)hb*Bn + m)*Hn + tid*4;
          p = wv4.x*gload(hp+0) + wv4.y*gload(hp+1)
            + wv4.z*gload(hp+2) + wv4.w*gload(hp+3);
        }
        if (wv_ < 4) {
          const float pr = wred(p);
          if (lane == 0) red[wv_] = pr;
        }
        __syncthreads();
        if (tid == 0)
          gstore(&dout[off + m*nout + o], red[0]+red[1]+red[2]+red[3] + bh_[o]);
      }
    }

    __syncthreads();
    if (tid < 8) {
      const int jj = tid >> 1, m = tid & 1;
      if (hasA) UPD_A(32);
      if (i == 33) UPD_B(31);
      if (i == 35) UPD_B(32);
    }

    if (i < 36) gbar(bar);
  }
  #undef ISSUE_W
  #undef UPD_A
  #undef UPD_B
}

extern "C" void kernel_launch(void* const* d_in, const int* in_sizes, int n_in,
                              void* d_out, int out_size, void* d_ws, size_t ws_size,
                              hipStream_t stream)
{
  (void)in_sizes; (void)n_in; (void)out_size; (void)ws_size;
  const float* x     = (const float*)d_in[0];
  const float* wih1  = (const float*)d_in[1];
  const float* whh1  = (const float*)d_in[2];
  const float* bih1  = (const float*)d_in[3];
  const float* bhh1  = (const float*)d_in[4];
  const float* wih2  = (const float*)d_in[5];
  const float* whh2  = (const float*)d_in[6];
  const float* bih2  = (const float*)d_in[7];
  const float* bhh2  = (const float*)d_in[8];
  const float* wobj1 = (const float*)d_in[9];
  const float* bobj1 = (const float*)d_in[10];
  const float* wrel  = (const float*)d_in[11];
  const float* brel  = (const float*)d_in[12];
  const float* wobj2 = (const float*)d_in[13];
  const float* bobj2 = (const float*)d_in[14];
  const float* embed = (const float*)d_in[15];
  float* dout = (float*)d_out;

  float* ws = (float*)d_ws;
  float* G1    = ws;                                   // 3600*66
  float* out1  = G1 + (size_t)G4n*Mn;                  // 33*2*900
  float* h2arr = out1 + (size_t)SEQn*Bn*Hn;            // 34*2*900 (rotating slots)
  unsigned* bar = (unsigned*)(h2arr + (size_t)34*Bn*Hn);

  hipMemsetAsync(G1, 0, (size_t)G4n*Mn*sizeof(float), stream);
  hipLaunchKernelGGL(k1_mfma, dim3(RB1*KS1), dim3(THR1), 0, stream, x, wih1, G1, bar);

  void* args[19];
  args[0]  = (void*)&G1;    args[1]  = (void*)&out1;  args[2]  = (void*)&h2arr;
  args[3]  = (void*)&whh1;  args[4]  = (void*)&wih2;  args[5]  = (void*)&whh2;
  args[6]  = (void*)&bih2;  args[7]  = (void*)&bhh2;  args[8]  = (void*)&bih1;
  args[9]  = (void*)&bhh1;  args[10] = (void*)&wobj1; args[11] = (void*)&bobj1;
  args[12] = (void*)&wrel;  args[13] = (void*)&brel;  args[14] = (void*)&wobj2;
  args[15] = (void*)&bobj2; args[16] = (void*)&embed; args[17] = (void*)&dout;
  args[18] = (void*)&bar;
  hipLaunchCooperativeKernel((void*)k_rec, dim3(NBLK), dim3(512), args, 0, stream);
}